// Round 2
// baseline (5122.933 us; speedup 1.0000x reference)
//
#include <hip/hip_runtime.h>
#include <math.h>

// ---------------------------------------------------------------------------
// Setup kernel v2: build weighted CG tensor C[9][9][9] from tp_w.
// Parallelized over all 363 path-block elements; factorial lookup table.
// ---------------------------------------------------------------------------

struct cd_t { double re, im; };
__device__ inline cd_t cmul(cd_t a, cd_t b) {
    return { a.re * b.re - a.im * b.im, a.re * b.im + a.im * b.re };
}

__device__ const double FTAB[13] = {
    1., 1., 2., 6., 24., 120., 720., 5040., 40320., 362880.,
    3628800., 39916800., 479001600.
};

__device__ double su2cg(int j1, int j2, int j3, int m1, int m2, int m3) {
    if (m1 + m2 != m3) return 0.0;
    double pre = sqrt((2.0 * j3 + 1.0) * FTAB[j3 + j1 - j2] * FTAB[j3 - j1 + j2] * FTAB[j1 + j2 - j3]
                      * FTAB[j3 + m3] * FTAB[j3 - m3]
                      / (FTAB[j1 + j2 + j3 + 1] * FTAB[j1 - m1] * FTAB[j1 + m1]
                         * FTAB[j2 - m2] * FTAB[j2 + m2]));
    double S = 0.0;
    for (int v = 0; v <= j1 + j2 + j3; ++v) {
        int b1 = j3 - j1 + j2 - v;
        int b2 = j3 + m3 - v;
        int b3 = v + j1 - j2 - m3;
        int b4 = j2 + j3 + m1 - v;
        int b5 = j1 - m1 + v;
        if (b1 < 0 || b2 < 0 || b3 < 0 || b4 < 0 || b5 < 0) continue;
        double term = FTAB[b4] * FTAB[b5] / (FTAB[v] * FTAB[b1] * FTAB[b2] * FTAB[b3]);
        S += ((v + j2 + m2) & 1) ? -term : term;
    }
    return pre * S;
}

// Entry (row r, col c) of e3nn change_basis_real_to_complex(l), incl (-i)^l phase.
__device__ cd_t qentry(int l, int r, int c) {
    const double s = 0.70710678118654752440;
    cd_t v = { 0.0, 0.0 };
    int m = r - l;
    if (m < 0) {
        if (c == l - m)      v = { s, 0.0 };    // col l+|m|
        else if (c == l + m) v = { 0.0, -s };   // col l-|m|
    } else if (m == 0) {
        if (c == l) v = { 1.0, 0.0 };
    } else {
        double sg = (m & 1) ? -1.0 : 1.0;
        if (c == l + m)      v = { sg * s, 0.0 };
        else if (c == l - m) v = { 0.0, sg * s };
    }
    if (l == 1)      v = { v.im, -v.re };   // * (-i)
    else if (l == 2) v = { -v.re, -v.im };  // * (-1)
    return v;
}

__device__ const int PA[11]  = { 0,0,0,1,1,1,1,2,2,2,2 };
__device__ const int PB[11]  = { 0,1,2,0,1,1,2,0,1,2,2 };
__device__ const int PC[11]  = { 0,1,2,1,0,2,1,2,1,0,2 };
__device__ const int OFF[11] = { 0,1,10,35,44,53,98,143,168,213,238 };
__device__ const int SZ[11]  = { 1,9,25,9,9,45,45,25,45,25,125 };
__device__ const double FANIN[3] = { 3.0, 4.0, 4.0 };

#define NEL 363

__global__ void setup_C_kernel(const float* __restrict__ tpw, float* __restrict__ Cd) {
    __shared__ double Rsh[NEL];
    __shared__ double scsh[11];
    int t = threadIdx.x;

    for (int u = t; u < 729; u += 384) Cd[u] = 0.0f;
    __syncthreads();

    int p = 0, a = 0, b = 0, c = 0, j = 0, l2 = 0, m = 0;
    if (t < NEL) {
        int rem = t;
        #pragma unroll
        for (int q = 10; q >= 1; --q) if (t >= OFF[q] && p == 0) { p = q; }
        rem = t - OFF[p];
        a = PA[p]; b = PB[p]; c = PC[p];
        int nb = 2 * b + 1, nc = 2 * c + 1;
        j  = rem / (nb * nc);
        l2 = (rem / nc) % nb;
        m  = rem % nc;

        double R = 0.0;
        for (int i = 0; i < 2 * a + 1; ++i) {
            for (int k = 0; k < 2 * b + 1; ++k) {
                int m3 = (i - a) + (k - b);
                if (m3 < -c || m3 > c) continue;
                double g = su2cg(a, b, c, i - a, k - b, m3);
                if (g == 0.0) continue;
                cd_t q1 = qentry(a, i, j);
                cd_t q2 = qentry(b, k, l2);
                cd_t q3 = qentry(c, m3 + c, m);
                cd_t t12 = cmul(q1, q2);
                R += (t12.re * q3.re + t12.im * q3.im) * g;  // Re(t12 * conj(q3))
            }
        }
        Rsh[t] = R;
    }
    __syncthreads();

    if (t < 11) {
        double nrm = 0.0;
        int o = OFF[t], n = SZ[t];
        for (int u = 0; u < n; ++u) nrm += Rsh[o + u] * Rsh[o + u];
        int cc = PC[t];
        scsh[t] = (double)tpw[t] * sqrt((2.0 * cc + 1.0) / FANIN[cc]) / sqrt(nrm);
    }
    __syncthreads();

    if (t < NEL) {
        int nb = 2 * b + 1, nc = 2 * c + 1;
        (void)nb;
        Cd[(a * a + j) * 81 + (b * b + l2) * 9 + (c * c + m)] = (float)(Rsh[t] * scsh[p]);
    }
}

// ---------------------------------------------------------------------------
// Main kernel: TPV=2 items per thread, <=128 VGPR for 4+ waves/SIMD.
// ---------------------------------------------------------------------------

#define TPV 2

__device__ constexpr int ALLOWC[3][3] = { {1, 2, 4}, {2, 5, 2}, {4, 2, 5} };

__global__ __launch_bounds__(256, 4) void tp_main_kernel(
        const float* __restrict__ x, const float* __restrict__ y,
        float* __restrict__ out,
        const float* __restrict__ Cg,
        const float* __restrict__ Wfx, const float* __restrict__ bfx,
        const float* __restrict__ Wfy, const float* __restrict__ bfy,
        long n_sets) {
    __shared__ float Cl[729];
    __shared__ float Wxs[81];
    __shared__ float Wys[81];
    __shared__ float bs[9];

    int t = threadIdx.x;
    for (int u = t; u < 729; u += 256) Cl[u] = Cg[u];
    if (t < 81) { Wxs[t] = Wfx[t]; Wys[t] = Wfy[t]; }
    if (t < 9)  { bs[t] = bfx[t] + bfy[t]; }
    __syncthreads();

    long set = (long)blockIdx.x * blockDim.x + t;
    if (set >= n_sets) return;

    const float2* x2 = reinterpret_cast<const float2*>(x) + set * 9;
    const float2* y2 = reinterpret_cast<const float2*>(y) + set * 9;
    float2* o2 = reinterpret_cast<float2*>(out) + set * 9;

    float xs[18], ys[18];   // item-major: xs[v*9+i]
    float os[18];           // k-major pairs: os[k*2+v] (packed-math friendly)

    #pragma unroll
    for (int q = 0; q < 9; ++q) {
        float2 ax = x2[q]; xs[2 * q] = ax.x; xs[2 * q + 1] = ax.y;
        float2 ay = y2[q]; ys[2 * q] = ay.x; ys[2 * q + 1] = ay.y;
    }

    #pragma unroll
    for (int k = 0; k < 9; ++k) {
        float bb = bs[k];
        os[2 * k] = bb; os[2 * k + 1] = bb;
    }

    // linear branches
    #pragma unroll
    for (int k = 0; k < 9; ++k) {
        #pragma unroll
        for (int i = 0; i < 9; ++i) {
            float wx = Wxs[k * 9 + i];
            float wy = Wys[k * 9 + i];
            os[2 * k + 0] += wx * xs[i]     + wy * ys[i];
            os[2 * k + 1] += wx * xs[9 + i] + wy * ys[9 + i];
        }
    }

    // tensor product over allowed (a,b,c) blocks
    #pragma unroll
    for (int a = 0; a < 3; ++a) {
        #pragma unroll
        for (int b = 0; b < 3; ++b) {
            #pragma unroll
            for (int di = 0; di < 2 * a + 1; ++di) {
                #pragma unroll
                for (int dj = 0; dj < 2 * b + 1; ++dj) {
                    const int i = a * a + di;
                    const int j = b * b + dj;
                    float p0 = xs[i]     * ys[j];
                    float p1 = xs[9 + i] * ys[9 + j];
                    #pragma unroll
                    for (int c = 0; c < 3; ++c) {
                        if (ALLOWC[a][b] & (1 << c)) {
                            #pragma unroll
                            for (int dk = 0; dk < 2 * c + 1; ++dk) {
                                const int k = c * c + dk;
                                float cv = Cl[(i * 9 + j) * 9 + k];
                                os[2 * k + 0] += cv * p0;
                                os[2 * k + 1] += cv * p1;
                            }
                        }
                    }
                }
            }
        }
    }

    // repack to item-major and store
    float lin[18];
    #pragma unroll
    for (int k = 0; k < 9; ++k) {
        lin[k]     = os[2 * k];
        lin[9 + k] = os[2 * k + 1];
    }
    #pragma unroll
    for (int q = 0; q < 9; ++q) {
        o2[q] = make_float2(lin[2 * q], lin[2 * q + 1]);
    }
}

// ---------------------------------------------------------------------------

extern "C" void kernel_launch(void* const* d_in, const int* in_sizes, int n_in,
                              void* d_out, int out_size, void* d_ws, size_t ws_size,
                              hipStream_t stream) {
    const float* x   = (const float*)d_in[0];
    const float* y   = (const float*)d_in[1];
    const float* tpw = (const float*)d_in[2];
    const float* Wfx = (const float*)d_in[3];
    const float* bfx = (const float*)d_in[4];
    const float* Wfy = (const float*)d_in[5];
    const float* bfy = (const float*)d_in[6];
    float* out = (float*)d_out;
    float* Cd = (float*)d_ws;   // 729 floats

    hipLaunchKernelGGL(setup_C_kernel, dim3(1), dim3(384), 0, stream, tpw, Cd);

    long n_items = (long)out_size / 9;              // 16777216
    long n_sets = (n_items + TPV - 1) / TPV;        // 8388608
    int block = 256;
    long grid = (n_sets + block - 1) / block;       // 32768

    hipLaunchKernelGGL(tp_main_kernel, dim3((unsigned)grid), dim3(block), 0, stream,
                       x, y, out, Cd, Wfx, bfx, Wfy, bfy, n_sets);
}

// Round 3
// 3417.402 us; speedup vs baseline: 1.4991x; 1.4991x over previous
//
#include <hip/hip_runtime.h>

// ===========================================================================
// Compile-time construction of the e3nn real Wigner-3j path tensor.
// K[i][j][k] = w3j_block(a,b,c)[di,dj,dk] / ||block|| * sqrt((2c+1)/fanin(c))
// so that runtime C[i,j,k] = tpw[path(i,j,k)] * K[i][j][k].
// ===========================================================================
namespace cg {

constexpr double csqrt(double x) {
    double g = x < 1.0 ? 1.0 : x;
    for (int i = 0; i < 64; ++i) g = 0.5 * (g + x / g);
    return g;
}
constexpr double fact(int n) { double r = 1.0; for (int i = 2; i <= n; ++i) r *= (double)i; return r; }

constexpr double su2cg(int j1, int j2, int j3, int m1, int m2, int m3) {
    if (m1 + m2 != m3) return 0.0;
    double pre = csqrt((2.0*j3+1.0)*fact(j3+j1-j2)*fact(j3-j1+j2)*fact(j1+j2-j3)
                       *fact(j3+m3)*fact(j3-m3)
                       /(fact(j1+j2+j3+1)*fact(j1-m1)*fact(j1+m1)*fact(j2-m2)*fact(j2+m2)));
    double S = 0.0;
    for (int v = 0; v <= j1 + j2 + j3; ++v) {
        int b1 = j3-j1+j2-v, b2 = j3+m3-v, b3 = v+j1-j2-m3, b4 = j2+j3+m1-v, b5 = j1-m1+v;
        if (b1 < 0 || b2 < 0 || b3 < 0 || b4 < 0 || b5 < 0) continue;
        double term = fact(b4)*fact(b5)/(fact(v)*fact(b1)*fact(b2)*fact(b3));
        S += ((v + j2 + m2) & 1) ? -term : term;
    }
    return pre * S;
}

struct CD { double re, im; };
constexpr CD cmul(CD a, CD b) { return { a.re*b.re - a.im*b.im, a.re*b.im + a.im*b.re }; }

// entry (row r, col c) of e3nn change_basis_real_to_complex(l), incl (-i)^l
constexpr CD qent(int l, int r, int c) {
    const double s = 0.70710678118654752440;
    CD v{0.0, 0.0};
    int m = r - l;
    if (m < 0)       { if (c == l - m) v = { s, 0.0 }; else if (c == l + m) v = { 0.0, -s }; }
    else if (m == 0) { if (c == l)     v = { 1.0, 0.0 }; }
    else             { double sg = (m & 1) ? -1.0 : 1.0;
                       if (c == l + m) v = { sg*s, 0.0 }; else if (c == l - m) v = { 0.0, sg*s }; }
    if      (l == 1) v = { v.im, -v.re };   // *(-i)
    else if (l == 2) v = { -v.re, -v.im };  // *(-1)
    return v;
}

constexpr int PA_[11] = {0,0,0,1,1,1,1,2,2,2,2};
constexpr int PB_[11] = {0,1,2,0,1,1,2,0,1,2,2};
constexpr int PC_[11] = {0,1,2,1,0,2,1,2,1,0,2};
constexpr double FAN_[3] = {3.0, 4.0, 4.0};

struct KTab { float v[9][9][9]; };

constexpr KTab buildK() {
    KTab T{};
    for (int p = 0; p < 11; ++p) {
        const int a = PA_[p], b = PB_[p], c = PC_[p];
        double cgt[5][5] = {};
        for (int i = 0; i < 2*a+1; ++i)
            for (int k = 0; k < 2*b+1; ++k) {
                int m3 = (i-a) + (k-b);
                cgt[i][k] = (m3 >= -c && m3 <= c) ? su2cg(a,b,c,i-a,k-b,m3) : 0.0;
            }
        double R[5][5][5] = {};
        double nrm = 0.0;
        for (int j = 0; j < 2*a+1; ++j)
            for (int l = 0; l < 2*b+1; ++l)
                for (int m = 0; m < 2*c+1; ++m) {
                    double re = 0.0;
                    for (int i = 0; i < 2*a+1; ++i)
                        for (int k = 0; k < 2*b+1; ++k) {
                            double g = cgt[i][k];
                            if (g == 0.0) continue;
                            int n = (i-a) + (k-b) + c;
                            CD t12 = cmul(qent(a,i,j), qent(b,k,l));
                            CD q3  = qent(c,n,m);          // conj applied via +im*im
                            re += (t12.re*q3.re + t12.im*q3.im) * g;
                        }
                    R[j][l][m] = re;
                    nrm += re*re;
                }
        double sc = csqrt((2.0*c+1.0)/FAN_[c]) / csqrt(nrm);
        for (int j = 0; j < 2*a+1; ++j)
            for (int l = 0; l < 2*b+1; ++l)
                for (int m = 0; m < 2*c+1; ++m)
                    T.v[a*a+j][b*b+l][c*c+m] = (float)(R[j][l][m] * sc);
    }
    return T;
}

constexpr KTab KT = buildK();

constexpr int pathOf(int a, int b, int c) {
    for (int p = 0; p < 11; ++p) if (PA_[p]==a && PB_[p]==b && PC_[p]==c) return p;
    return 0;
}
constexpr bool allowedC(int a, int b, int c) {
    int lo = a > b ? a - b : b - a;
    return c >= lo && c <= a + b && (((a + b + c) & 1) == 0);
}
constexpr bool anyNZ(int i, int j) {
    for (int k = 0; k < 9; ++k) if (KT.v[i][j][k] != 0.0f) return true;
    return false;
}
constexpr bool rowNZ(int a, int b, int c, int dk) {
    for (int di = 0; di < 2*a+1; ++di)
        for (int dj = 0; dj < 2*b+1; ++dj)
            if (KT.v[a*a+di][b*b+dj][c*c+dk] != 0.0f) return true;
    return false;
}

} // namespace cg

// ===========================================================================
// Main kernel. 256 threads, 2 items/thread, 512 items/block.
// Coalesced float4 tile load -> LDS -> per-thread compute (all C constants
// folded at compile time) -> LDS -> coalesced float4 store.
// LDS: 2*18KB tiles + 0.9KB weights ~= 37.8KB -> 4 blocks/CU.
// ===========================================================================

#define TPV   2
#define BLK   256
#define ITEMS (BLK * TPV)      // 512
#define TILEF (ITEMS * 9)      // 4608 floats
#define TILE4 (TILEF / 4)      // 1152 float4

__global__ __launch_bounds__(BLK) void tp_main_kernel(
        const float* __restrict__ x, const float* __restrict__ y,
        float* __restrict__ out, const float* __restrict__ tpw,
        const float* __restrict__ Wfx, const float* __restrict__ bfx,
        const float* __restrict__ Wfy, const float* __restrict__ bfy,
        long n_items)
{
    __shared__ __align__(16) float tx[TILEF];
    __shared__ __align__(16) float ty[TILEF];
    __shared__ __align__(16) float Wc[9][24];   // [k][0..8]=Wfx row, [k][12..20]=Wfy row
    __shared__ float bs[9];

    const int t = threadIdx.x;
    const long blk = blockIdx.x;

    if (t < 81) { Wc[t/9][t%9] = Wfx[t]; Wc[t/9][12 + t%9] = Wfy[t]; }
    if (t < 9)  bs[t] = bfx[t] + bfy[t];

    // 11 path weights, forced wave-uniform -> SGPRs
    float w[11];
    #pragma unroll
    for (int p = 0; p < 11; ++p) {
        union { float f; int i; } u;
        u.f = tpw[p];
        u.i = __builtin_amdgcn_readfirstlane(u.i);
        w[p] = u.f;
    }

    // ---- cooperative coalesced tile loads ----
    const long nf4 = n_items * 9 / 4;
    const float4* xg = reinterpret_cast<const float4*>(x);
    const float4* yg = reinterpret_cast<const float4*>(y);
    float4* tx4 = reinterpret_cast<float4*>(tx);
    float4* ty4 = reinterpret_cast<float4*>(ty);
    #pragma unroll
    for (int r = 0; r < 5; ++r) {
        int idx = r * BLK + t;
        long g4 = blk * TILE4 + idx;
        if (idx < TILE4 && g4 < nf4) { tx4[idx] = xg[g4]; ty4[idx] = yg[g4]; }
    }
    __syncthreads();

    const long set = blk * BLK + t;
    const bool active = (set * TPV) < n_items;

    float acc[18];   // acc[v*9+k]
    if (active) {
        // per-thread item pair: floats [t*18, t*18+18)
        float xl[18], yl[18];   // xl[v*9+i]
        const float2* txr = reinterpret_cast<const float2*>(&tx[t * 18]);
        const float2* tyr = reinterpret_cast<const float2*>(&ty[t * 18]);
        #pragma unroll
        for (int q = 0; q < 9; ++q) {
            float2 a2 = txr[q]; xl[2*q] = a2.x; xl[2*q+1] = a2.y;
            float2 b2 = tyr[q]; yl[2*q] = b2.x; yl[2*q+1] = b2.y;
        }

        // init biases
        #pragma unroll
        for (int k = 0; k < 9; ++k) { float bb = bs[k]; acc[k] = bb; acc[9+k] = bb; }

        // linear branches: acc[k] += sum_i Wfx[k,i]*x_i + Wfy[k,i]*y_i
        #pragma unroll
        for (int k = 0; k < 9; ++k) {
            float4 wxa = *reinterpret_cast<const float4*>(&Wc[k][0]);
            float4 wxb = *reinterpret_cast<const float4*>(&Wc[k][4]);
            float  wx8 = Wc[k][8];
            float4 wya = *reinterpret_cast<const float4*>(&Wc[k][12]);
            float4 wyb = *reinterpret_cast<const float4*>(&Wc[k][16]);
            float  wy8 = Wc[k][20];
            const float wxr[9] = {wxa.x,wxa.y,wxa.z,wxa.w,wxb.x,wxb.y,wxb.z,wxb.w,wx8};
            const float wyr[9] = {wya.x,wya.y,wya.z,wya.w,wyb.x,wyb.y,wyb.z,wyb.w,wy8};
            float s0 = acc[k], s1 = acc[9+k];
            #pragma unroll
            for (int i = 0; i < 9; ++i) {
                s0 += wxr[i]*xl[i]   + wyr[i]*yl[i];
                s1 += wxr[i]*xl[9+i] + wyr[i]*yl[9+i];
            }
            acc[k] = s0; acc[9+k] = s1;
        }

        // tensor product: compile-time-folded sparse 3j constants
        #pragma unroll
        for (int a = 0; a < 3; ++a) {
            #pragma unroll
            for (int b = 0; b < 3; ++b) {
                float pa[3][5][2];
                #pragma unroll
                for (int c = 0; c < 3; ++c)
                    #pragma unroll
                    for (int dk = 0; dk < 5; ++dk) { pa[c][dk][0] = 0.f; pa[c][dk][1] = 0.f; }

                #pragma unroll
                for (int di = 0; di < 2*a+1; ++di) {
                    #pragma unroll
                    for (int dj = 0; dj < 2*b+1; ++dj) {
                        const int i = a*a + di, j = b*b + dj;
                        if (cg::anyNZ(i, j)) {              // folds to constant
                            const float p0 = xl[i]   * yl[j];
                            const float p1 = xl[9+i] * yl[9+j];
                            #pragma unroll
                            for (int c = 0; c < 3; ++c) {
                                #pragma unroll
                                for (int dk = 0; dk < 2*c+1; ++dk) {
                                    const float kv = cg::KT.v[i][j][c*c + dk];  // constant
                                    if (kv != 0.0f) {
                                        pa[c][dk][0] += kv * p0;
                                        pa[c][dk][1] += kv * p1;
                                    }
                                }
                            }
                        }
                    }
                }
                #pragma unroll
                for (int c = 0; c < 3; ++c) {
                    if (cg::allowedC(a, b, c)) {
                        const int p = cg::pathOf(a, b, c);
                        #pragma unroll
                        for (int dk = 0; dk < 2*c+1; ++dk) {
                            if (cg::rowNZ(a, b, c, dk)) {
                                acc[c*c + dk]     += w[p] * pa[c][dk][0];
                                acc[9 + c*c + dk] += w[p] * pa[c][dk][1];
                            }
                        }
                    }
                }
            }
        }
    }

    // ---- staged coalesced store (reuse tx tile) ----
    __syncthreads();              // everyone done reading tiles
    if (active) {
        float2* txw = reinterpret_cast<float2*>(&tx[t * 18]);
        #pragma unroll
        for (int q = 0; q < 9; ++q) txw[q] = make_float2(acc[2*q], acc[2*q+1]);
    }
    __syncthreads();
    float4* og = reinterpret_cast<float4*>(out);
    #pragma unroll
    for (int r = 0; r < 5; ++r) {
        int idx = r * BLK + t;
        long g4 = blk * TILE4 + idx;
        if (idx < TILE4 && g4 < nf4) og[g4] = tx4[idx];
    }
}

// ===========================================================================

extern "C" void kernel_launch(void* const* d_in, const int* in_sizes, int n_in,
                              void* d_out, int out_size, void* d_ws, size_t ws_size,
                              hipStream_t stream) {
    const float* x   = (const float*)d_in[0];
    const float* y   = (const float*)d_in[1];
    const float* tpw = (const float*)d_in[2];
    const float* Wfx = (const float*)d_in[3];
    const float* bfx = (const float*)d_in[4];
    const float* Wfy = (const float*)d_in[5];
    const float* bfy = (const float*)d_in[6];
    float* out = (float*)d_out;

    long n_items = (long)out_size / 9;                      // 16,777,216
    long grid = (n_items + ITEMS - 1) / ITEMS;              // 32,768

    hipLaunchKernelGGL(tp_main_kernel, dim3((unsigned)grid), dim3(BLK), 0, stream,
                       x, y, out, tpw, Wfx, bfx, Wfy, bfy, n_items);
}